// Round 1
// baseline (332.139 us; speedup 1.0000x reference)
//
#include <hip/hip_runtime.h>
#include <math.h>

namespace {
constexpr int kB = 65536;      // rows
constexpr int kC = 300;        // cards/options dim
constexpr int kA = 32;         // archetype dim
constexpr int kBlock = 256;
}

__global__ __launch_bounds__(kBlock) void draftbot_kernel(
    const float* __restrict__ X,
    const float* __restrict__ W,
    float* __restrict__ out)
{
    // per-thread option bitmask (10 words of 32 bits covering c=0..299),
    // kept in LDS so runtime word-index doesn't force scratch (rule #20).
    __shared__ unsigned int obits[kBlock * 11];  // stride 11: conflict-benign
    const int tid = threadIdx.x;
    const long r = (long)blockIdx.x * kBlock + tid;
    if (r >= kB) return;

    const float4* __restrict__ opts4  = reinterpret_cast<const float4*>(X + r * (2L * kC));
    const float4* __restrict__ cards4 = opts4 + (kC / 4);      // 75 float4
    float4* __restrict__ out4 = reinterpret_cast<float4*>(out + r * (long)kC);

    unsigned int* mybits = &obits[tid * 11];

    // ---- pass 0: options -> bitmask (stored to LDS) ----
    #pragma unroll
    for (int w = 0; w < 10; ++w) {
        constexpr int kFull = 8;
        const int nq = (w == 9) ? 3 : kFull;
        unsigned int bits = 0u;
        #pragma unroll
        for (int q = 0; q < kFull; ++q) {
            if (q < nq) {  // nq is compile-time per unrolled w
                float4 o = opts4[w * 8 + q];
                const int sh = q * 4;
                if (o.x != 0.0f) bits |= (1u << sh);
                if (o.y != 0.0f) bits |= (2u << sh);
                if (o.z != 0.0f) bits |= (4u << sh);
                if (o.w != 0.0f) bits |= (8u << sh);
            }
        }
        mybits[w] = bits;
    }

    // ---- pass 1: ap = cards @ W + 1  (W via uniform indices -> s_load) ----
    float ap[kA];
    #pragma unroll
    for (int a = 0; a < kA; ++a) ap[a] = 1.0f;
    for (int q = 0; q < kC / 4; ++q) {
        const float4 cd = cards4[q];
        const float* __restrict__ wr = W + q * (4 * kA);
        #pragma unroll
        for (int a = 0; a < kA; ++a) ap[a] = fmaf(cd.x, wr[a], ap[a]);
        #pragma unroll
        for (int a = 0; a < kA; ++a) ap[a] = fmaf(cd.y, wr[kA + a], ap[a]);
        #pragma unroll
        for (int a = 0; a < kA; ++a) ap[a] = fmaf(cd.z, wr[2 * kA + a], ap[a]);
        #pragma unroll
        for (int a = 0; a < kA; ++a) ap[a] = fmaf(cd.w, wr[3 * kA + a], ap[a]);
    }

    // computes the 4 masked scores for quad qq (c = 4*qq .. 4*qq+3)
    auto score_quad = [&](int qq, unsigned int bits, int qofs, float* xv) {
        #pragma unroll
        for (int j = 0; j < 4; ++j) {
            const float* __restrict__ wr = W + (qq * 4 + j) * kA;
            float e0 = 0.f, e1 = 0.f, e2 = 0.f, e3 = 0.f;
            #pragma unroll
            for (int a = 0; a < kA; a += 4) {
                e0 = fmaf(ap[a + 0], wr[a + 0], e0);
                e1 = fmaf(ap[a + 1], wr[a + 1], e1);
                e2 = fmaf(ap[a + 2], wr[a + 2], e2);
                e3 = fmaf(ap[a + 3], wr[a + 3], e3);
            }
            const float dot = (e0 + e1) + (e2 + e3);
            xv[j] = ((bits >> (qofs + j)) & 1u) ? dot : 0.0f;
        }
    };

    // ---- pass 2: row max (zeros where option==0 participate, as in ref) ----
    float m0 = -INFINITY, m1 = -INFINITY, m2 = -INFINITY, m3 = -INFINITY;
    for (int w = 0; w < 10; ++w) {
        const unsigned int bits = mybits[w];
        const int nq = (w == 9) ? 3 : 8;
        for (int q = 0; q < nq; ++q) {
            float xv[4];
            score_quad(w * 8 + q, bits, q * 4, xv);
            m0 = fmaxf(m0, xv[0]);
            m1 = fmaxf(m1, xv[1]);
            m2 = fmaxf(m2, xv[2]);
            m3 = fmaxf(m3, xv[3]);
        }
    }
    const float M = fmaxf(fmaxf(m0, m1), fmaxf(m2, m3));

    // ---- pass 3: sum of s * exp(x - M*s) ----
    auto term = [&](float x) {
        const float sg = (x > 0.f ? 1.f : 0.f) - (x < 0.f ? 1.f : 0.f);
        return sg * __expf(x - M * sg);
    };
    float s0 = 0.f, s1 = 0.f, s2 = 0.f, s3 = 0.f;
    for (int w = 0; w < 10; ++w) {
        const unsigned int bits = mybits[w];
        const int nq = (w == 9) ? 3 : 8;
        for (int q = 0; q < nq; ++q) {
            float xv[4];
            score_quad(w * 8 + q, bits, q * 4, xv);
            s0 += term(xv[0]);
            s1 += term(xv[1]);
            s2 += term(xv[2]);
            s3 += term(xv[3]);
        }
    }
    const float S = (s0 + s1) + (s2 + s3);
    const float lse = __logf(S);

    // ---- pass 4: output = s * (x - M*s - lse) ----
    auto outv = [&](float x) {
        const float sg = (x > 0.f ? 1.f : 0.f) - (x < 0.f ? 1.f : 0.f);
        return sg * (x - M * sg - lse);
    };
    for (int w = 0; w < 10; ++w) {
        const unsigned int bits = mybits[w];
        const int nq = (w == 9) ? 3 : 8;
        for (int q = 0; q < nq; ++q) {
            float xv[4];
            score_quad(w * 8 + q, bits, q * 4, xv);
            float4 o;
            o.x = outv(xv[0]);
            o.y = outv(xv[1]);
            o.z = outv(xv[2]);
            o.w = outv(xv[3]);
            out4[w * 8 + q] = o;
        }
    }
}

extern "C" void kernel_launch(void* const* d_in, const int* in_sizes, int n_in,
                              void* d_out, int out_size, void* d_ws, size_t ws_size,
                              hipStream_t stream) {
    const float* X = (const float*)d_in[0];
    const float* W = (const float*)d_in[1];
    float* out = (float*)d_out;
    dim3 grid(kB / kBlock);
    dim3 block(kBlock);
    hipLaunchKernelGGL(draftbot_kernel, grid, block, 0, stream, X, W, out);
}